// Round 16
// baseline (3173.851 us; speedup 1.0000x reference)
//
#include <hip/hip_runtime.h>
#include <stdint.h>

// Persistent-LSTM, round 16: r15 pacing + self-validating tagged data
// (removes the producer's serial h-store-ack hop).
//  - 256 WGs x 128 threads (2 waves). g = bid&3 (rows 16g..16g+15, XCD-pair
//    locality), m = bid>>2 (u-cols 8m..8m+7).
//  - hbuf: TAGGED u32 [2][64][512], word = (t<<16)|bf16(h_t) for step t
//    (parity t&1). Embedded tags are the correctness AUTHORITY; the spread
//    cheap tags [4][64][16] are only a pacing gate (r14's lesson: without a
//    gate, speculation churns; r15's lesson: with ack-ordered tags, the ack
//    hop is serial. This round: gate without ordering).
//  - Producer tail: vmcnt(0) certifies x-prefetch (issued ~0.8us earlier,
//    cheap) -> tagged h store FIRE-AND-FORGET -> s_barrier -> tid0 tag ->
//    w0 probe -> nt out store. No data ack: tag may race data; the
//    consumer's embedded-tag validation catches it (rare reload).
//  - Consumer: x-phase (prefetched regs) -> w0 probe check under vmcnt(1)
//    (also absorbs our own h/tag store acks, hidden under x-phase) ->
//    re-poll if stale -> barrier -> 16 tagged h loads + 8 x-prefetch ->
//    vmcnt(8) (certifies h: pending = out+h16+xpf8 -> <=8 leaves xpf only;
//    in-order retire) -> umin-validate -> rare {sleep, reload, vmcnt(0)}
//    loop -> perm repack -> 16 MFMAs.
//  - WAR safety: publishing h_{t+1} requires validating h_t, which requires
//    every WG published h_t, which requires their h_{t-1} loads complete ->
//    parity overwrite races nothing. Monotone progress -> no deadlock.
//  - Keeps: XCD-pair mapping, zbuf parity double-buffer (3 barriers/step),
//    probe-before-out tail, nontemporal out.

#define Tt   1024
#define Uu   512
#define G4U  2048
#define NWG  256
#define NTHR 128
#define TAGSTRIDE 16                               // u32s per tag line (64 B)

#define WF_ELEMS (2 * 24 * 64 * 8)                 // 24576 bf16 = 48 KB
#define WF_BYTES (WF_ELEMS * 2)
#define ZB_PLANE (16 * 17)
#define ZB_HALF  (4 * ZB_PLANE)                    // floats per parity buffer
#define SMEM_BYTES (WF_BYTES + 2 * ZB_HALF * 4)    // 48 KB + 8704 B

typedef short  bf16x8 __attribute__((ext_vector_type(8)));
typedef float  f32x4  __attribute__((ext_vector_type(4)));
typedef int    int4v  __attribute__((ext_vector_type(4)));
typedef unsigned int u32;

__device__ __forceinline__ unsigned short f2bf(float f) {
  u32 u = __builtin_bit_cast(u32, f);
  u += 0x7fffu + ((u >> 16) & 1u);                 // RNE (finite inputs)
  return (unsigned short)(u >> 16);
}
__device__ __forceinline__ u32 umin32(u32 a, u32 b) { return a < b ? a : b; }

// sc1 = agent scope (IF$); plain = cached (x, read-only).
__device__ __forceinline__ int4v ld16_ag(const u32* p) {
  int4v r;
  asm volatile("global_load_dwordx4 %0, %1, off sc1"
               : "=v"(r) : "v"(p) : "memory");
  return r;
}
__device__ __forceinline__ int4v ld16_nc(const float* p) {
  int4v r;
  asm volatile("global_load_dwordx4 %0, %1, off"
               : "=v"(r) : "v"(p) : "memory");
  return r;
}
__device__ __forceinline__ void store4_ag(u32* p, u32 v) {
  asm volatile("global_store_dword %0, %1, off sc1"
               :: "v"(p), "v"(v) : "memory");
}

__device__ __forceinline__ float sigf(float z) {
  return __builtin_amdgcn_rcpf(1.f + __expf(-z));
}
__device__ __forceinline__ float tanh_fast(float v) {
  const float e = __expf(-2.f * fabsf(v));
  const float r = (1.f - e) * __builtin_amdgcn_rcpf(1.f + e);
  return copysignf(r, v);
}

extern "C" __global__ void __launch_bounds__(NTHR, 1)
lstm_persistent(const float* __restrict__ x,
                const float* __restrict__ Wk,
                const float* __restrict__ Rk,
                const float* __restrict__ bias,
                float* __restrict__ out,
                u32* __restrict__ hbuf,             // [2][64][512] tagged u32
                u32* __restrict__ tags)             // [4][64][16] spread, pacing
{
  extern __shared__ char smem[];
  unsigned short* wf   = (unsigned short*)smem;            // [nt][kt][lane][8]
  float*          zbuf = (float*)(smem + WF_BYTES);        // [2][w*nt][16][17]

  const int bid = blockIdx.x;
  const int tid = threadIdx.x;
  const int w   = tid >> 6;
  const int l   = tid & 63;
  const int g   = bid & 3;         // row group on XCD pair {g, g+4}
  const int m   = bid >> 2;        // u-cols 8m..8m+7

  // ---- one-time weight staging into MFMA B-fragment order ----
  for (int i = tid; i < WF_ELEMS; i += NTHR) {
    const int j    = i & 7;
    const int lane = (i >> 3) & 63;
    const int kt   = (i >> 9) % 24;
    const int nt   = (i >> 9) / 24;
    const int k    = kt * 32 + ((lane >> 4) << 3) + j;     // 0..767
    const int n    = nt * 16 + (lane & 15);                // 0..31
    const int zc   = (n >> 3) * Uu + m * 8 + (n & 7);      // gate*512 + u
    const float v  = (k < 256) ? Wk[(size_t)k * G4U + zc]
                               : Rk[(size_t)(k - 256) * G4U + zc];
    wf[i] = f2bf(v);
  }
  __syncthreads();

  // ---- preload x-part weight fragments (kt = 2q+w, q=0..3) ----
  bf16x8 wfx[4][2];
  #pragma unroll
  for (int q = 0; q < 4; ++q)
    #pragma unroll
    for (int nt = 0; nt < 2; ++nt)
      wfx[q][nt] = *(const bf16x8*)(wf + (((nt * 24) + (2 * q + w)) * 64 + l) * 8);

  // ---- combine-role constants (one (row,u) pair per thread) ----
  const int row_c = tid >> 3;                  // 0..15
  const int uu    = tid & 7;
  const int b_out = g * 16 + row_c;
  const int u_out = m * 8 + uu;
  float breg[4];
  #pragma unroll
  for (int gg = 0; gg < 4; ++gg) breg[gg] = bias[gg * Uu + u_out];
  float creg = 0.f;

  // ---- load-role constants (lane-level, MFMA A-fragment) ----
  const int b_ld = g * 16 + (l & 15);
  const int kq   = (l >> 4) * 8;
  const u32* tagp = tags + ((size_t)g * 64 + l) * TAGSTRIDE;  // producer l's line

  // ---- pre-loop: prefetch x(t=0); issue + drain initial probe ----
  int4v xv[4][2];
  {
    const float* xp0 = x + ((size_t)b_ld * Tt + 0) * 256 + kq;
    #pragma unroll
    for (int q = 0; q < 4; ++q) {
      const int kt = 2 * q + w;
      xv[q][0] = ld16_nc(xp0 + kt * 32);
      xv[q][1] = ld16_nc(xp0 + kt * 32 + 4);
    }
  }
  u32 tv = 0;
  if (w == 0)
    asm volatile("global_load_dword %0, %1, off sc1"
                 : "=v"(tv) : "v"(tagp) : "memory");
  asm volatile("s_waitcnt vmcnt(0)" ::: "memory");
  __builtin_amdgcn_sched_barrier(0);

  for (int t = 0; t < Tt; ++t) {
    // ---- x phase: pure cvt + 8 MFMAs (x regs prefetched & certified) ----
    f32x4 aX0 = {0.f, 0.f, 0.f, 0.f};
    f32x4 aX1 = {0.f, 0.f, 0.f, 0.f};
    #pragma unroll
    for (int q = 0; q < 4; ++q) {
      const f32x4 v0 = __builtin_bit_cast(f32x4, xv[q][0]);
      const f32x4 v1 = __builtin_bit_cast(f32x4, xv[q][1]);
      int r0, r1, r2, r3;
      asm("v_cvt_pk_bf16_f32 %0, %1, %2" : "=v"(r0) : "v"(v0[0]), "v"(v0[1]));
      asm("v_cvt_pk_bf16_f32 %0, %1, %2" : "=v"(r1) : "v"(v0[2]), "v"(v0[3]));
      asm("v_cvt_pk_bf16_f32 %0, %1, %2" : "=v"(r2) : "v"(v1[0]), "v"(v1[1]));
      asm("v_cvt_pk_bf16_f32 %0, %1, %2" : "=v"(r3) : "v"(v1[2]), "v"(v1[3]));
      const int4v ai = {r0, r1, r2, r3};
      const bf16x8 a = __builtin_bit_cast(bf16x8, ai);
      aX0 = __builtin_amdgcn_mfma_f32_16x16x32_bf16(a, wfx[q][0], aX0, 0, 0, 0);
      aX1 = __builtin_amdgcn_mfma_f32_16x16x32_bf16(a, wfx[q][1], aX1, 0, 0, 0);
    }

    // ---- acquire gate: wave 0 checks prior probe via counted vmcnt(1) ----
    // (w0 pending, issue order: h store, tag, probe, out -> vmcnt(1)
    //  certifies the probe while the slow out ack stays pending; our own
    //  h/tag store acks absorb here, hidden under the x-phase)
    if (w == 0) {
      asm volatile("s_waitcnt vmcnt(1)" ::: "memory");
      __builtin_amdgcn_sched_barrier(0);
      while (!__all(tv >= (u32)t)) {
        __builtin_amdgcn_s_sleep(1);
        asm volatile("global_load_dword %0, %1, off sc1\n\ts_waitcnt vmcnt(0)"
                     : "=v"(tv) : "v"(tagp) : "memory");
        __builtin_amdgcn_sched_barrier(0);
      }
    }
    __builtin_amdgcn_s_barrier();                // hand-off: gate passed
    __builtin_amdgcn_sched_barrier(0);

    // ---- tagged h loads (16), then x prefetch for t+1 (8) ----
    const u32* hp = hbuf + ((size_t)(t & 1) * 64 + b_ld) * Uu + kq;
    int4v hf[16];
    #pragma unroll
    for (int q = 0; q < 8; ++q) {
      hf[2 * q]     = ld16_ag(hp + (2 * q + w) * 32);
      hf[2 * q + 1] = ld16_ag(hp + (2 * q + w) * 32 + 4);
    }
    {
      const int tn = (t + 1 < Tt) ? t + 1 : t;   // clamp: avoid OOB read
      const float* xpn = x + ((size_t)b_ld * Tt + tn) * 256 + kq;
      #pragma unroll
      for (int q = 0; q < 4; ++q) {
        const int kt = 2 * q + w;
        xv[q][0] = ld16_nc(xpn + kt * 32);
        xv[q][1] = ld16_nc(xpn + kt * 32 + 4);
      }
    }

    // ---- certify h (out+h16 retired; xpf stays in flight), validate ----
    asm volatile("s_waitcnt vmcnt(8)" ::: "memory");
    __builtin_amdgcn_sched_barrier(0);
    for (;;) {
      u32 m0 = ~0u, m1 = ~0u, m2 = ~0u, m3 = ~0u;
      #pragma unroll
      for (int q = 0; q < 16; ++q) {
        m0 = umin32(m0, (u32)hf[q][0]);
        m1 = umin32(m1, (u32)hf[q][1]);
        m2 = umin32(m2, (u32)hf[q][2]);
        m3 = umin32(m3, (u32)hf[q][3]);
      }
      const u32 mv = umin32(umin32(m0, m1), umin32(m2, m3));
      if (__all((mv >> 16) == (u32)t)) break;      // all words fresh
      __builtin_amdgcn_s_sleep(1);                 // rare: tag beat data
      #pragma unroll
      for (int q = 0; q < 8; ++q) {
        hf[2 * q]     = ld16_ag(hp + (2 * q + w) * 32);
        hf[2 * q + 1] = ld16_ag(hp + (2 * q + w) * 32 + 4);
      }
      asm volatile("s_waitcnt vmcnt(0)" ::: "memory");
      __builtin_amdgcn_sched_barrier(0);
    }

    // ---- h phase: repack + 16 MFMAs on validated data ----
    f32x4 aH0 = {0.f, 0.f, 0.f, 0.f};
    f32x4 aH1 = {0.f, 0.f, 0.f, 0.f};
    #pragma unroll
    for (int q = 0; q < 8; ++q) {
      const int kt = 8 + 2 * q + w;
      const u32 w0_ = __builtin_amdgcn_perm((u32)hf[2*q][1],   (u32)hf[2*q][0],   0x05040100u);
      const u32 w1_ = __builtin_amdgcn_perm((u32)hf[2*q][3],   (u32)hf[2*q][2],   0x05040100u);
      const u32 w2_ = __builtin_amdgcn_perm((u32)hf[2*q+1][1], (u32)hf[2*q+1][0], 0x05040100u);
      const u32 w3_ = __builtin_amdgcn_perm((u32)hf[2*q+1][3], (u32)hf[2*q+1][2], 0x05040100u);
      const int4v ai = {(int)w0_, (int)w1_, (int)w2_, (int)w3_};
      const bf16x8 a = __builtin_bit_cast(bf16x8, ai);
      const bf16x8 b0 = *(const bf16x8*)(wf + ((0 * 24 + kt) * 64 + l) * 8);
      const bf16x8 b1 = *(const bf16x8*)(wf + ((1 * 24 + kt) * 64 + l) * 8);
      aH0 = __builtin_amdgcn_mfma_f32_16x16x32_bf16(a, b0, aH0, 0, 0, 0);
      aH1 = __builtin_amdgcn_mfma_f32_16x16x32_bf16(a, b1, aH1, 0, 0, 0);
    }

    const f32x4 z0 = aX0 + aH0;
    const f32x4 z1 = aX1 + aH1;

    // ---- z reduce through parity-double-buffered zbuf (1 barrier) ----
    float* zb = zbuf + (t & 1) * ZB_HALF;
    {
      float* zw = zb + ((w * 2 + 0) * 16 + (l >> 4) * 4) * 17 + (l & 15);
      #pragma unroll
      for (int r = 0; r < 4; ++r) {
        zw[r * 17]           = z0[r];
        zw[r * 17 + 16 * 17] = z1[r];            // nt=1 plane
      }
    }
    __syncthreads();

    // ---- gate math (fp32), cell update ----
    float z[4];
    #pragma unroll
    for (int gg = 0; gg < 4; ++gg) {
      const int n  = gg * 8 + uu;
      const int nt = n >> 4, nc = n & 15;
      z[gg] = zb[((0 + nt) * 16 + row_c) * 17 + nc]
            + zb[((2 + nt) * 16 + row_c) * 17 + nc]
            + breg[gg];
    }
    const float ig = sigf(z[0]);
    const float fg = sigf(z[1]);
    const float og = sigf(z[3]);
    const float cc = fg * creg + ig * z[2];
    creg = cc;
    const float hh = og * cc;

    // ---- release: certify x-pf -> tagged h store (NO ack) -> barrier
    //      -> tag -> probe -> out ----
    asm volatile("s_waitcnt vmcnt(0)" ::: "memory");   // x-pf only (cheap)
    __builtin_amdgcn_sched_barrier(0);
    const u32 hw = ((u32)(t + 1) << 16) | (u32)f2bf(hh);
    store4_ag(hbuf + ((size_t)((t + 1) & 1) * 64 + b_out) * Uu + u_out, hw);
    __builtin_amdgcn_s_barrier();                // all 128 h stores issued
    __builtin_amdgcn_sched_barrier(0);
    if (tid == 0)
      store4_ag(tags + ((size_t)g * 64 + m) * TAGSTRIDE, (u32)(t + 1));
    if (w == 0)
      asm volatile("global_load_dword %0, %1, off sc1"
                   : "=v"(tv) : "v"(tagp) : "memory");  // next probe BEFORE out
    {
      const float ov = tanh_fast(hh);
      float* op = out + ((size_t)b_out * Tt + t) * Uu + u_out;
      asm volatile("global_store_dword %0, %1, off nt"
                   :: "v"(op), "v"(ov) : "memory");     // slow ack stays last
    }
  }
}

extern "C" void kernel_launch(void* const* d_in, const int* in_sizes, int n_in,
                              void* d_out, int out_size, void* d_ws, size_t ws_size,
                              hipStream_t stream) {
  const float* x    = (const float*)d_in[0];
  const float* Wk   = (const float*)d_in[1];
  const float* Rk   = (const float*)d_in[2];
  const float* bias = (const float*)d_in[3];
  float* out = (float*)d_out;
  u32* hbuf = (u32*)d_ws;
  u32* tags = (u32*)((char*)d_ws + (size_t)2 * 64 * Uu * sizeof(u32));

  // zeroed hbuf == valid tag-0 h_0 = 0 (both parities); tags 0 = published.
  (void)hipMemsetAsync(d_ws, 0,
                       (size_t)2 * 64 * Uu * sizeof(u32)
                         + (size_t)4 * 64 * TAGSTRIDE * sizeof(u32),
                       stream);

  (void)hipFuncSetAttribute((const void*)lstm_persistent,
                            hipFuncAttributeMaxDynamicSharedMemorySize,
                            SMEM_BYTES);

  hipLaunchKernelGGL(lstm_persistent, dim3(NWG), dim3(NTHR), SMEM_BYTES, stream,
                     x, Wk, Rk, bias, out, hbuf, tags);
}